// Round 4
// baseline (311.376 us; speedup 1.0000x reference)
//
#include <hip/hip_runtime.h>
#include <hip/hip_bf16.h>

typedef __attribute__((ext_vector_type(8))) short short8v;
typedef __attribute__((ext_vector_type(4))) float f32x4;

#define B_ 2
#define NTOK 4096
#define DMODEL 1024
#define HEADS_ 16
#define DH 64
#define SEG_ 512
#define PMEM 16
#define ROWS 8192      // B_*NTOK
#define QKVC 3072

// ---------------- RMSNorm -> bf16 ----------------
__global__ __launch_bounds__(256) void rmsnorm_bf16(const float* __restrict__ seq,
                                                    const float* __restrict__ g,
                                                    __hip_bfloat16* __restrict__ x) {
    int row = blockIdx.x;
    const float4* in = (const float4*)(seq + (size_t)row * DMODEL);
    int tid = threadIdx.x;
    float4 v = in[tid];
    float ss = v.x*v.x + v.y*v.y + v.z*v.z + v.w*v.w;
    #pragma unroll
    for (int off = 32; off >= 1; off >>= 1) ss += __shfl_xor(ss, off, 64);
    __shared__ float red[4];
    if ((tid & 63) == 0) red[tid >> 6] = ss;
    __syncthreads();
    float tot = red[0] + red[1] + red[2] + red[3];
    float scale = rsqrtf(tot * (1.0f/(float)DMODEL) + 1.1920929e-7f);
    float4 gv = ((const float4*)g)[tid];
    union { ushort4 u; __hip_bfloat16 h[4]; } pk;
    pk.h[0] = __float2bfloat16(v.x*scale*gv.x);
    pk.h[1] = __float2bfloat16(v.y*scale*gv.y);
    pk.h[2] = __float2bfloat16(v.z*scale*gv.z);
    pk.h[3] = __float2bfloat16(v.w*scale*gv.w);
    ((ushort4*)(x + (size_t)row * DMODEL))[tid] = pk.u;
}

// ---------------- transpose + convert: W[K,N] f32 -> Wt[N,K] bf16 ----------
__global__ __launch_bounds__(256) void transpose_bf16(const float* __restrict__ W,
                                                      __hip_bfloat16* __restrict__ Wt,
                                                      int K, int N) {
    __shared__ float t[32][33];
    int n0 = blockIdx.x * 32, k0 = blockIdx.y * 32;
    int c = threadIdx.x & 31, r = threadIdx.x >> 5;
    #pragma unroll
    for (int rr = 0; rr < 32; rr += 8)
        t[rr + r][c] = W[(size_t)(k0 + rr + r)*N + n0 + c];
    __syncthreads();
    #pragma unroll
    for (int rr = 0; rr < 32; rr += 8)
        Wt[(size_t)(n0 + rr + r)*K + k0 + c] = __float2bfloat16(t[c][rr + r]);
}

// ---------------- bf16 MFMA GEMM: C[M,N] = A[M,K] @ Bt[N,K]^T, C f32 -------
__device__ __forceinline__ void gld16(const __hip_bfloat16* g, __hip_bfloat16* l) {
    __builtin_amdgcn_global_load_lds((const __attribute__((address_space(1))) void*)g,
                                     (__attribute__((address_space(3))) void*)l, 16, 0, 0);
}

__global__ __launch_bounds__(256, 2) void gemm_bf16(const __hip_bfloat16* __restrict__ A,
                                                    const __hip_bfloat16* __restrict__ Bt,
                                                    float* __restrict__ C,
                                                    int M, int N, int K) {
    __shared__ __hip_bfloat16 As[128*32];
    __shared__ __hip_bfloat16 Bs[128*32];
    const int tid = threadIdx.x;
    const int wid = tid >> 6, lane = tid & 63;
    const int bm = blockIdx.y * 128, bn = blockIdx.x * 128;
    const int wm = (wid >> 1) * 64, wn = (wid & 1) * 64;

    f32x4 acc[4][4];
    #pragma unroll
    for (int i = 0; i < 4; ++i)
        #pragma unroll
        for (int j = 0; j < 4; ++j)
            acc[i][j] = (f32x4){0.f, 0.f, 0.f, 0.f};

    const int c0 = wid*64 + lane;
    const int c1 = 256 + c0;
    const int r0 = c0 >> 2, kg0 = (c0 & 3) << 3;
    const int r1 = c1 >> 2, kg1 = (c1 & 3) << 3;
    const __hip_bfloat16* A0 = A + (size_t)(bm + r0)*K + kg0;
    const __hip_bfloat16* A1 = A + (size_t)(bm + r1)*K + kg1;
    const __hip_bfloat16* B0 = Bt + (size_t)(bn + r0)*K + kg0;
    const __hip_bfloat16* B1 = Bt + (size_t)(bn + r1)*K + kg1;

    const int fr = lane & 15;
    const int fk = (lane >> 4) << 3;

    for (int k0 = 0; k0 < K; k0 += 32) {
        gld16(A0 + k0, As + wid*512);
        gld16(A1 + k0, As + 2048 + wid*512);
        gld16(B0 + k0, Bs + wid*512);
        gld16(B1 + k0, Bs + 2048 + wid*512);
        __syncthreads();

        short8v a[4], b[4];
        #pragma unroll
        for (int mt = 0; mt < 4; ++mt)
            a[mt] = *(const short8v*)&As[(wm + mt*16 + fr)*32 + fk];
        #pragma unroll
        for (int nt = 0; nt < 4; ++nt)
            b[nt] = *(const short8v*)&Bs[(wn + nt*16 + fr)*32 + fk];
        #pragma unroll
        for (int mt = 0; mt < 4; ++mt)
            #pragma unroll
            for (int nt = 0; nt < 4; ++nt)
                acc[mt][nt] = __builtin_amdgcn_mfma_f32_16x16x32_bf16(a[mt], b[nt], acc[mt][nt], 0, 0, 0);
        __syncthreads();
    }

    const int rsub = (lane >> 4) << 2;
    #pragma unroll
    for (int mt = 0; mt < 4; ++mt) {
        int rbase = bm + wm + mt*16 + rsub;
        #pragma unroll
        for (int nt = 0; nt < 4; ++nt) {
            int col = bn + wn + nt*16 + fr;
            #pragma unroll
            for (int r = 0; r < 4; ++r)
                C[(size_t)(rbase + r)*N + col] = acc[mt][nt][r];
        }
    }
}

// ---------------- RoPE: cos/sin table + apply -------------------------------
__global__ __launch_bounds__(256) void rope_table(float* __restrict__ tab) {
    int idx = blockIdx.x*256 + threadIdx.x;     // NTOK*32 threads
    int n = idx >> 5, p = idx & 31;
    float inv = powf(10000.f, -(float)p * (1.f/32.f));
    float a = (float)n * inv;
    float sn, cs;
    sincosf(a, &sn, &cs);
    tab[(size_t)n*64 + 2*p]     = cs;
    tab[(size_t)n*64 + 2*p + 1] = sn;
}

__global__ __launch_bounds__(256) void rope_apply(float* __restrict__ qkv,
                                                  const float* __restrict__ tab) {
    int idx = blockIdx.x*256 + threadIdx.x;
    int row = idx >> 9;
    int c4  = (idx & 511) << 2;
    int n   = row & (NTOK - 1);
    int d   = c4 & (DH - 1);
    float4 t4 = *(const float4*)&tab[(size_t)n*64 + d];   // cos0,sin0,cos1,sin1
    float* ptr = qkv + (size_t)row*QKVC + c4;
    float4 v = *(float4*)ptr;
    float4 o;
    o.x = v.x*t4.x - v.y*t4.y;
    o.y = v.y*t4.x + v.x*t4.y;
    o.z = v.z*t4.z - v.w*t4.w;
    o.w = v.w*t4.z + v.z*t4.w;
    *(float4*)ptr = o;
}

// ---------------- MFMA flash attention ------------------------------------
// grid (16 seg, 16 head, 2 rb), 512 threads = 8 waves. 32 groups of 16 q-rows;
// block rb owns groups with parity rb; wave w owns groups {2w+rb, 30-2w+rb}
// (complementary pairing balances causal work). KV tiles of 64 keys
// (tile0 = 16 pmem + 48 seg keys), double-buffered LDS. K [key][d],
// V transposed [d][key], P per-wave [16][64]; rows XOR-swizzled (row&7)<<4.
__device__ __forceinline__ void stage_load(const float* __restrict__ qkv,
                                           const float* __restrict__ pm,
                                           int h, int srow, int tt, int skey, int sdg,
                                           float4 kv[4]) {
    int kg = tt*64 + skey;
    if (kg < PMEM) {
        const float* kp = pm + ((size_t)h*PMEM + kg)*DH + sdg;
        const float* vp = pm + ((size_t)(HEADS_ + h)*PMEM + kg)*DH + sdg;
        kv[0] = *(const float4*)kp;      kv[1] = *(const float4*)(kp + 4);
        kv[2] = *(const float4*)vp;      kv[3] = *(const float4*)(vp + 4);
    } else {
        int r = min(kg - PMEM, SEG_ - 1);   // clamp tail (masked anyway)
        const float* bp = qkv + (size_t)(srow + r)*QKVC + h*DH + sdg;
        kv[0] = *(const float4*)(bp + 1024); kv[1] = *(const float4*)(bp + 1028);
        kv[2] = *(const float4*)(bp + 2048); kv[3] = *(const float4*)(bp + 2052);
    }
}

__device__ __forceinline__ void stage_write(__hip_bfloat16* Kb, __hip_bfloat16* Vb,
                                            int skey, int sdg, const float4 kv[4]) {
    union { uint4 u; __hip_bfloat16 hh[8]; } pk;
    const float kf[8] = {kv[0].x,kv[0].y,kv[0].z,kv[0].w, kv[1].x,kv[1].y,kv[1].z,kv[1].w};
    #pragma unroll
    for (int j = 0; j < 8; ++j) pk.hh[j] = __float2bfloat16(kf[j]);
    *(uint4*)((char*)Kb + ((skey*128 + sdg*2) ^ ((skey&7)<<4))) = pk.u;
    const float vf[8] = {kv[2].x,kv[2].y,kv[2].z,kv[2].w, kv[3].x,kv[3].y,kv[3].z,kv[3].w};
    #pragma unroll
    for (int j = 0; j < 8; ++j) {
        int d = sdg + j;
        *(__hip_bfloat16*)((char*)Vb + ((d*128 + skey*2) ^ ((d&7)<<4))) = __float2bfloat16(vf[j]);
    }
}

__global__ __launch_bounds__(512, 4) void attn_mfma(const float* __restrict__ qkv,
                                                    const float* __restrict__ pm,
                                                    __hip_bfloat16* __restrict__ ao) {
    __shared__ __hip_bfloat16 KB[2][4096];
    __shared__ __hip_bfloat16 VB[2][4096];
    __shared__ __hip_bfloat16 PB[8][1024];

    const int s = blockIdx.x, h = blockIdx.y, rb = blockIdx.z;
    const int srow = (s >> 3)*NTOK + (s & 7)*SEG_;
    const int tid = threadIdx.x;
    const int w = tid >> 6, lane = tid & 63;
    const int g = lane >> 4, fr = lane & 15;
    const int rsub = g * 4;
    char* Pw = (char*)&PB[w][0];

    const int grp0 = 2*w + rb;
    const int grp1 = 30 - 2*w + rb;
    const int tmax = 7 + rb;

    // Q fragments (scaled by dh^-0.5), resident for the whole kernel
    short8v aq[2][2];
    #pragma unroll
    for (int mt = 0; mt < 2; ++mt) {
        int grp = mt ? grp1 : grp0;
        const float* qp = qkv + (size_t)(srow + grp*16 + fr)*QKVC + h*DH;
        #pragma unroll
        for (int ks = 0; ks < 2; ++ks) {
            float4 q0 = *(const float4*)(qp + ks*32 + g*8);
            float4 q1 = *(const float4*)(qp + ks*32 + g*8 + 4);
            union { short8v v; __hip_bfloat16 hh[8]; } u;
            u.hh[0] = __float2bfloat16(q0.x*0.125f); u.hh[1] = __float2bfloat16(q0.y*0.125f);
            u.hh[2] = __float2bfloat16(q0.z*0.125f); u.hh[3] = __float2bfloat16(q0.w*0.125f);
            u.hh[4] = __float2bfloat16(q1.x*0.125f); u.hh[5] = __float2bfloat16(q1.y*0.125f);
            u.hh[6] = __float2bfloat16(q1.z*0.125f); u.hh[7] = __float2bfloat16(q1.w*0.125f);
            aq[mt][ks] = u.v;
        }
    }

    f32x4 accO[2][4];
    float m_[2][4], l_[2][4];
    #pragma unroll
    for (int mt = 0; mt < 2; ++mt) {
        #pragma unroll
        for (int dt = 0; dt < 4; ++dt) accO[mt][dt] = (f32x4){0.f,0.f,0.f,0.f};
        #pragma unroll
        for (int r = 0; r < 4; ++r) { m_[mt][r] = -1e30f; l_[mt][r] = 0.f; }
    }

    const int skey = tid >> 3, sdg = (tid & 7) * 8;

    {   // prologue: stage tile 0
        float4 kv[4];
        stage_load(qkv, pm, h, srow, 0, skey, sdg, kv);
        stage_write(&KB[0][0], &VB[0][0], skey, sdg, kv);
    }
    __syncthreads();

    for (int t = 0; t <= tmax; ++t) {
        const int bf = t & 1;
        float4 kvn[4];
        if (t < tmax) stage_load(qkv, pm, h, srow, t + 1, skey, sdg, kvn);

        char* Kb = (char*)&KB[bf][0];
        char* Vb = (char*)&VB[bf][0];

        short8v bk[4][2];
        #pragma unroll
        for (int nt = 0; nt < 4; ++nt)
            #pragma unroll
            for (int ks = 0; ks < 2; ++ks) {
                int row = nt*16 + fr;
                bk[nt][ks] = *(const short8v*)(Kb + ((row*128 + ks*64 + g*16) ^ ((row&7)<<4)));
            }

        #pragma unroll
        for (int mt = 0; mt < 2; ++mt) {
            const int qb = (mt ? grp1 : grp0) * 16;
            if (t > 0 && t*64 > qb + 31) continue;       // fully masked tile

            f32x4 sA[4];
            #pragma unroll
            for (int nt = 0; nt < 4; ++nt) sA[nt] = (f32x4){0.f,0.f,0.f,0.f};
            #pragma unroll
            for (int ks = 0; ks < 2; ++ks)
                #pragma unroll
                for (int nt = 0; nt < 4; ++nt)
                    sA[nt] = __builtin_amdgcn_mfma_f32_16x16x32_bf16(aq[mt][ks], bk[nt][ks], sA[nt], 0, 0, 0);

            if (!(t*64 + 63 <= qb + 16)) {               // need masking
                #pragma unroll
                for (int nt = 0; nt < 4; ++nt) {
                    int kg2 = t*64 + nt*16 + fr;
                    #pragma unroll
                    for (int r = 0; r < 4; ++r) {
                        int irow = qb + rsub + r;
                        if (!((kg2 < PMEM) || (kg2 <= irow + PMEM))) sA[nt][r] = -1e30f;
                    }
                }
            }

            float mx[4], corr[4], rs[4];
            #pragma unroll
            for (int r = 0; r < 4; ++r)
                mx[r] = fmaxf(fmaxf(sA[0][r], sA[1][r]), fmaxf(sA[2][r], sA[3][r]));
            #pragma unroll
            for (int r = 0; r < 4; ++r) {
                #pragma unroll
                for (int off = 1; off <= 8; off <<= 1)
                    mx[r] = fmaxf(mx[r], __shfl_xor(mx[r], off, 64));
                float mn = fmaxf(m_[mt][r], mx[r]);
                corr[r] = __expf(m_[mt][r] - mn);
                m_[mt][r] = mn;
            }
            #pragma unroll
            for (int nt = 0; nt < 4; ++nt)
                #pragma unroll
                for (int r = 0; r < 4; ++r)
                    sA[nt][r] = __expf(sA[nt][r] - m_[mt][r]);
            #pragma unroll
            for (int r = 0; r < 4; ++r) {
                rs[r] = sA[0][r] + sA[1][r] + sA[2][r] + sA[3][r];
                #pragma unroll
                for (int off = 1; off <= 8; off <<= 1)
                    rs[r] += __shfl_xor(rs[r], off, 64);
                l_[mt][r] = l_[mt][r]*corr[r] + rs[r];
            }
            #pragma unroll
            for (int dt = 0; dt < 4; ++dt)
                #pragma unroll
                for (int r = 0; r < 4; ++r)
                    accO[mt][dt][r] *= corr[r];

            // P -> per-wave LDS (bf16), 16x64 tile
            #pragma unroll
            for (int nt = 0; nt < 4; ++nt)
                #pragma unroll
                for (int r = 0; r < 4; ++r) {
                    int row_l = rsub + r;
                    *(__hip_bfloat16*)(Pw + ((row_l*128 + (nt*16 + fr)*2) ^ ((row_l&7)<<4))) =
                        __float2bfloat16(sA[nt][r]);
                }

            // O += P @ V
            #pragma unroll
            for (int ks2 = 0; ks2 < 2; ++ks2) {
                short8v ap = *(const short8v*)(Pw + ((fr*128 + ks2*64 + g*16) ^ ((fr&7)<<4)));
                #pragma unroll
                for (int dt = 0; dt < 4; ++dt) {
                    int vrow = dt*16 + fr;
                    short8v bv = *(const short8v*)(Vb + ((vrow*128 + ks2*64 + g*16) ^ ((vrow&7)<<4)));
                    accO[mt][dt] = __builtin_amdgcn_mfma_f32_16x16x32_bf16(ap, bv, accO[mt][dt], 0, 0, 0);
                }
            }
        }

        if (t < tmax) stage_write(&KB[bf^1][0], &VB[bf^1][0], skey, sdg, kvn);
        __syncthreads();
    }

    // epilogue: O/l -> per-wave LDS -> coalesced bf16 stores
    #pragma unroll
    for (int mt = 0; mt < 2; ++mt) {
        const int grp = mt ? grp1 : grp0;
        float inv[4];
        #pragma unroll
        for (int r = 0; r < 4; ++r) inv[r] = 1.0f / l_[mt][r];
        #pragma unroll
        for (int dt = 0; dt < 4; ++dt)
            #pragma unroll
            for (int r = 0; r < 4; ++r) {
                int row_l = rsub + r;
                *(__hip_bfloat16*)(Pw + ((row_l*128 + (dt*16 + fr)*2) ^ ((row_l&7)<<4))) =
                    __float2bfloat16(accO[mt][dt][r] * inv[r]);
            }
        #pragma unroll
        for (int c = 0; c < 2; ++c) {
            int row_l = c*8 + (lane >> 3);
            size_t grow = (size_t)(srow + grp*16 + row_l);
            uint4 v = *(const uint4*)(Pw + ((row_l*128 + (lane&7)*16) ^ ((row_l&7)<<4)));
            *(uint4*)((char*)(ao + grow*DMODEL + h*DH) + (lane&7)*16) = v;
        }
    }
}

extern "C" void kernel_launch(void* const* d_in, const int* in_sizes, int n_in,
                              void* d_out, int out_size, void* d_ws, size_t ws_size,
                              hipStream_t stream) {
    const float* seq  = (const float*)d_in[0];
    const float* g    = (const float*)d_in[1];
    const float* wqkv = (const float*)d_in[2];
    const float* wout = (const float*)d_in[3];
    const float* pm   = (const float*)d_in[4];
    float* out = (float*)d_out;

    char* ws = (char*)d_ws;
    float* qkv            = (float*)ws;                                   // 96 MB
    __hip_bfloat16* xb    = (__hip_bfloat16*)(ws + 100663296);            // 16 MB (x, later ao)
    __hip_bfloat16* wqkvt = (__hip_bfloat16*)(ws + 100663296 + 16777216); // 6 MB
    __hip_bfloat16* woutt = (__hip_bfloat16*)(ws + 100663296 + 16777216 + 6291456); // 2 MB
    float* tab            = (float*)(ws + 100663296 + 16777216 + 6291456 + 2097152); // 1 MB

    rope_table<<<(NTOK*32)/256, 256, 0, stream>>>(tab);
    transpose_bf16<<<dim3(QKVC/32, DMODEL/32), 256, 0, stream>>>(wqkv, wqkvt, DMODEL, QKVC);
    transpose_bf16<<<dim3(DMODEL/32, DMODEL/32), 256, 0, stream>>>(wout, woutt, DMODEL, DMODEL);
    rmsnorm_bf16<<<ROWS, 256, 0, stream>>>(seq, g, xb);
    gemm_bf16<<<dim3(QKVC/128, ROWS/128), 256, 0, stream>>>(xb, wqkvt, qkv, ROWS, QKVC, DMODEL);
    rope_apply<<<(ROWS*2048/4)/256, 256, 0, stream>>>(qkv, tab);
    attn_mfma<<<dim3(16, 16, 2), 512, 0, stream>>>(qkv, pm, xb);
    gemm_bf16<<<dim3(DMODEL/128, ROWS/128), 256, 0, stream>>>(xb, woutt, out, ROWS, DMODEL, DMODEL);
}

// Round 5
// 218.916 us; speedup vs baseline: 1.4224x; 1.4224x over previous
//
#include <hip/hip_runtime.h>
#include <hip/hip_bf16.h>

typedef __attribute__((ext_vector_type(8))) short short8v;
typedef __attribute__((ext_vector_type(4))) float f32x4;

#define B_ 2
#define NTOK 4096
#define DMODEL 1024
#define HEADS_ 16
#define DH 64
#define SEG_ 512
#define PMEM 16
#define ROWS 8192      // B_*NTOK
#define QKVC 3072

// ---------------- RMSNorm -> bf16 ----------------
__global__ __launch_bounds__(256) void rmsnorm_bf16(const float* __restrict__ seq,
                                                    const float* __restrict__ g,
                                                    __hip_bfloat16* __restrict__ x) {
    int row = blockIdx.x;
    const float4* in = (const float4*)(seq + (size_t)row * DMODEL);
    int tid = threadIdx.x;
    float4 v = in[tid];
    float ss = v.x*v.x + v.y*v.y + v.z*v.z + v.w*v.w;
    #pragma unroll
    for (int off = 32; off >= 1; off >>= 1) ss += __shfl_xor(ss, off, 64);
    __shared__ float red[4];
    if ((tid & 63) == 0) red[tid >> 6] = ss;
    __syncthreads();
    float tot = red[0] + red[1] + red[2] + red[3];
    float scale = rsqrtf(tot * (1.0f/(float)DMODEL) + 1.1920929e-7f);
    float4 gv = ((const float4*)g)[tid];
    union { ushort4 u; __hip_bfloat16 h[4]; } pk;
    pk.h[0] = __float2bfloat16(v.x*scale*gv.x);
    pk.h[1] = __float2bfloat16(v.y*scale*gv.y);
    pk.h[2] = __float2bfloat16(v.z*scale*gv.z);
    pk.h[3] = __float2bfloat16(v.w*scale*gv.w);
    ((ushort4*)(x + (size_t)row * DMODEL))[tid] = pk.u;
}

// ---------------- transpose + convert: W[K,N] f32 -> Wt[N,K] bf16 ----------
__global__ __launch_bounds__(256) void transpose_bf16(const float* __restrict__ W,
                                                      __hip_bfloat16* __restrict__ Wt,
                                                      int K, int N) {
    __shared__ float t[32][33];
    int n0 = blockIdx.x * 32, k0 = blockIdx.y * 32;
    int c = threadIdx.x & 31, r = threadIdx.x >> 5;
    #pragma unroll
    for (int rr = 0; rr < 32; rr += 8)
        t[rr + r][c] = W[(size_t)(k0 + rr + r)*N + n0 + c];
    __syncthreads();
    #pragma unroll
    for (int rr = 0; rr < 32; rr += 8)
        Wt[(size_t)(n0 + rr + r)*K + k0 + c] = __float2bfloat16(t[c][rr + r]);
}

// ---------------- bf16 MFMA GEMM: C[M,N] = A[M,K] @ Bt[N,K]^T, C f32 -------
__device__ __forceinline__ void gld16(const __hip_bfloat16* g, __hip_bfloat16* l) {
    __builtin_amdgcn_global_load_lds((const __attribute__((address_space(1))) void*)g,
                                     (__attribute__((address_space(3))) void*)l, 16, 0, 0);
}

__global__ __launch_bounds__(256, 2) void gemm_bf16(const __hip_bfloat16* __restrict__ A,
                                                    const __hip_bfloat16* __restrict__ Bt,
                                                    float* __restrict__ C,
                                                    int M, int N, int K) {
    __shared__ __hip_bfloat16 As[128*32];
    __shared__ __hip_bfloat16 Bs[128*32];
    const int tid = threadIdx.x;
    const int wid = tid >> 6, lane = tid & 63;
    const int bm = blockIdx.y * 128, bn = blockIdx.x * 128;
    const int wm = (wid >> 1) * 64, wn = (wid & 1) * 64;

    f32x4 acc[4][4];
    #pragma unroll
    for (int i = 0; i < 4; ++i)
        #pragma unroll
        for (int j = 0; j < 4; ++j)
            acc[i][j] = (f32x4){0.f, 0.f, 0.f, 0.f};

    const int c0 = wid*64 + lane;
    const int c1 = 256 + c0;
    const int r0 = c0 >> 2, kg0 = (c0 & 3) << 3;
    const int r1 = c1 >> 2, kg1 = (c1 & 3) << 3;
    const __hip_bfloat16* A0 = A + (size_t)(bm + r0)*K + kg0;
    const __hip_bfloat16* A1 = A + (size_t)(bm + r1)*K + kg1;
    const __hip_bfloat16* B0 = Bt + (size_t)(bn + r0)*K + kg0;
    const __hip_bfloat16* B1 = Bt + (size_t)(bn + r1)*K + kg1;

    const int fr = lane & 15;
    const int fk = (lane >> 4) << 3;

    for (int k0 = 0; k0 < K; k0 += 32) {
        gld16(A0 + k0, As + wid*512);
        gld16(A1 + k0, As + 2048 + wid*512);
        gld16(B0 + k0, Bs + wid*512);
        gld16(B1 + k0, Bs + 2048 + wid*512);
        __syncthreads();

        short8v a[4], b[4];
        #pragma unroll
        for (int mt = 0; mt < 4; ++mt)
            a[mt] = *(const short8v*)&As[(wm + mt*16 + fr)*32 + fk];
        #pragma unroll
        for (int nt = 0; nt < 4; ++nt)
            b[nt] = *(const short8v*)&Bs[(wn + nt*16 + fr)*32 + fk];
        #pragma unroll
        for (int mt = 0; mt < 4; ++mt)
            #pragma unroll
            for (int nt = 0; nt < 4; ++nt)
                acc[mt][nt] = __builtin_amdgcn_mfma_f32_16x16x32_bf16(a[mt], b[nt], acc[mt][nt], 0, 0, 0);
        __syncthreads();
    }

    const int rsub = (lane >> 4) << 2;
    #pragma unroll
    for (int mt = 0; mt < 4; ++mt) {
        int rbase = bm + wm + mt*16 + rsub;
        #pragma unroll
        for (int nt = 0; nt < 4; ++nt) {
            int col = bn + wn + nt*16 + fr;
            #pragma unroll
            for (int r = 0; r < 4; ++r)
                C[(size_t)(rbase + r)*N + col] = acc[mt][nt][r];
        }
    }
}

// ---------------- RoPE: cos/sin table + apply -------------------------------
__global__ __launch_bounds__(256) void rope_table(float* __restrict__ tab) {
    int idx = blockIdx.x*256 + threadIdx.x;     // NTOK*32 threads
    int n = idx >> 5, p = idx & 31;
    float inv = powf(10000.f, -(float)p * (1.f/32.f));
    float a = (float)n * inv;
    float sn, cs;
    sincosf(a, &sn, &cs);
    tab[(size_t)n*64 + 2*p]     = cs;
    tab[(size_t)n*64 + 2*p + 1] = sn;
}

__global__ __launch_bounds__(256) void rope_apply(float* __restrict__ qkv,
                                                  const float* __restrict__ tab) {
    int idx = blockIdx.x*256 + threadIdx.x;
    int row = idx >> 9;
    int c4  = (idx & 511) << 2;
    int n   = row & (NTOK - 1);
    int d   = c4 & (DH - 1);
    float4 t4 = *(const float4*)&tab[(size_t)n*64 + d];   // cos0,sin0,cos1,sin1
    float* ptr = qkv + (size_t)row*QKVC + c4;
    float4 v = *(float4*)ptr;
    float4 o;
    o.x = v.x*t4.x - v.y*t4.y;
    o.y = v.y*t4.x + v.x*t4.y;
    o.z = v.z*t4.z - v.w*t4.w;
    o.w = v.w*t4.z + v.z*t4.w;
    *(float4*)ptr = o;
}

// ---------------- MFMA flash attention ------------------------------------
// grid (16 seg, 16 head, 2 rb), 512 threads = 8 waves. 32 groups of 16 q-rows;
// block rb owns groups with parity rb; wave w owns groups {2w+rb, 30-2w+rb}.
// KV tiles of 64 keys (tile0 = 16 pmem + 48 seg keys), double-buffered LDS.
// K [key][d], V transposed [d][key], P per-wave [16][64]; XOR swizzle (row&7)<<4.
// NOTE: __launch_bounds__(512,2) NOT (512,4) — the 4-waves/EU bound caps VGPR
// at 64 and spills 0.5 GB of scratch per dispatch (round-4 post-mortem).
__device__ __forceinline__ void stage_load(const float* __restrict__ qkv,
                                           const float* __restrict__ pm,
                                           int h, int srow, int tt, int skey, int sdg,
                                           float4 kv[4]) {
    int kg = tt*64 + skey;
    if (kg < PMEM) {
        const float* kp = pm + ((size_t)h*PMEM + kg)*DH + sdg;
        const float* vp = pm + ((size_t)(HEADS_ + h)*PMEM + kg)*DH + sdg;
        kv[0] = *(const float4*)kp;      kv[1] = *(const float4*)(kp + 4);
        kv[2] = *(const float4*)vp;      kv[3] = *(const float4*)(vp + 4);
    } else {
        int r = min(kg - PMEM, SEG_ - 1);   // clamp tail (masked anyway)
        const float* bp = qkv + (size_t)(srow + r)*QKVC + h*DH + sdg;
        kv[0] = *(const float4*)(bp + 1024); kv[1] = *(const float4*)(bp + 1028);
        kv[2] = *(const float4*)(bp + 2048); kv[3] = *(const float4*)(bp + 2052);
    }
}

__device__ __forceinline__ void stage_write(__hip_bfloat16* Kb, __hip_bfloat16* Vb,
                                            int skey, int sdg, const float4 kv[4]) {
    union { uint4 u; __hip_bfloat16 hh[8]; } pk;
    const float kf[8] = {kv[0].x,kv[0].y,kv[0].z,kv[0].w, kv[1].x,kv[1].y,kv[1].z,kv[1].w};
    #pragma unroll
    for (int j = 0; j < 8; ++j) pk.hh[j] = __float2bfloat16(kf[j]);
    *(uint4*)((char*)Kb + ((skey*128 + sdg*2) ^ ((skey&7)<<4))) = pk.u;
    const float vf[8] = {kv[2].x,kv[2].y,kv[2].z,kv[2].w, kv[3].x,kv[3].y,kv[3].z,kv[3].w};
    #pragma unroll
    for (int j = 0; j < 8; ++j) {
        int d = sdg + j;
        *(__hip_bfloat16*)((char*)Vb + ((d*128 + skey*2) ^ ((d&7)<<4))) = __float2bfloat16(vf[j]);
    }
}

__global__ __launch_bounds__(512, 2) void attn_mfma(const float* __restrict__ qkv,
                                                    const float* __restrict__ pm,
                                                    __hip_bfloat16* __restrict__ ao) {
    __shared__ __hip_bfloat16 KB[2][4096];
    __shared__ __hip_bfloat16 VB[2][4096];
    __shared__ __hip_bfloat16 PB[8][1024];

    const int s = blockIdx.x, h = blockIdx.y, rb = blockIdx.z;
    const int srow = (s >> 3)*NTOK + (s & 7)*SEG_;
    const int tid = threadIdx.x;
    const int w = tid >> 6, lane = tid & 63;
    const int g = lane >> 4, fr = lane & 15;
    const int rsub = g * 4;
    char* Pw = (char*)&PB[w][0];

    const int grp0 = 2*w + rb;
    const int grp1 = 30 - 2*w + rb;
    const int tmax = 7 + rb;

    // Q fragments (scaled by dh^-0.5), resident for the whole kernel
    short8v aq[2][2];
    #pragma unroll
    for (int mt = 0; mt < 2; ++mt) {
        int grp = mt ? grp1 : grp0;
        const float* qp = qkv + (size_t)(srow + grp*16 + fr)*QKVC + h*DH;
        #pragma unroll
        for (int ks = 0; ks < 2; ++ks) {
            float4 q0 = *(const float4*)(qp + ks*32 + g*8);
            float4 q1 = *(const float4*)(qp + ks*32 + g*8 + 4);
            union { short8v v; __hip_bfloat16 hh[8]; } u;
            u.hh[0] = __float2bfloat16(q0.x*0.125f); u.hh[1] = __float2bfloat16(q0.y*0.125f);
            u.hh[2] = __float2bfloat16(q0.z*0.125f); u.hh[3] = __float2bfloat16(q0.w*0.125f);
            u.hh[4] = __float2bfloat16(q1.x*0.125f); u.hh[5] = __float2bfloat16(q1.y*0.125f);
            u.hh[6] = __float2bfloat16(q1.z*0.125f); u.hh[7] = __float2bfloat16(q1.w*0.125f);
            aq[mt][ks] = u.v;
        }
    }

    f32x4 accO[2][4];
    float m_[2][4], l_[2][4];
    #pragma unroll
    for (int mt = 0; mt < 2; ++mt) {
        #pragma unroll
        for (int dt = 0; dt < 4; ++dt) accO[mt][dt] = (f32x4){0.f,0.f,0.f,0.f};
        #pragma unroll
        for (int r = 0; r < 4; ++r) { m_[mt][r] = -1e30f; l_[mt][r] = 0.f; }
    }

    const int skey = tid >> 3, sdg = (tid & 7) * 8;

    {   // prologue: stage tile 0
        float4 kv[4];
        stage_load(qkv, pm, h, srow, 0, skey, sdg, kv);
        stage_write(&KB[0][0], &VB[0][0], skey, sdg, kv);
    }
    __syncthreads();

    for (int t = 0; t <= tmax; ++t) {
        const int bf = t & 1;
        float4 kvn[4];
        if (t < tmax) stage_load(qkv, pm, h, srow, t + 1, skey, sdg, kvn);

        char* Kb = (char*)&KB[bf][0];
        char* Vb = (char*)&VB[bf][0];

        short8v bk[4][2];
        #pragma unroll
        for (int nt = 0; nt < 4; ++nt)
            #pragma unroll
            for (int ks = 0; ks < 2; ++ks) {
                int row = nt*16 + fr;
                bk[nt][ks] = *(const short8v*)(Kb + ((row*128 + ks*64 + g*16) ^ ((row&7)<<4)));
            }

        #pragma unroll
        for (int mt = 0; mt < 2; ++mt) {
            const int qb = (mt ? grp1 : grp0) * 16;
            if (t > 0 && t*64 > qb + 31) continue;       // fully masked tile

            f32x4 sA[4];
            #pragma unroll
            for (int nt = 0; nt < 4; ++nt) sA[nt] = (f32x4){0.f,0.f,0.f,0.f};
            #pragma unroll
            for (int ks = 0; ks < 2; ++ks)
                #pragma unroll
                for (int nt = 0; nt < 4; ++nt)
                    sA[nt] = __builtin_amdgcn_mfma_f32_16x16x32_bf16(aq[mt][ks], bk[nt][ks], sA[nt], 0, 0, 0);

            if (!(t*64 + 63 <= qb + 16)) {               // need masking
                #pragma unroll
                for (int nt = 0; nt < 4; ++nt) {
                    int kg2 = t*64 + nt*16 + fr;
                    #pragma unroll
                    for (int r = 0; r < 4; ++r) {
                        int irow = qb + rsub + r;
                        if (!((kg2 < PMEM) || (kg2 <= irow + PMEM))) sA[nt][r] = -1e30f;
                    }
                }
            }

            float mx[4], corr[4], rs[4];
            #pragma unroll
            for (int r = 0; r < 4; ++r)
                mx[r] = fmaxf(fmaxf(sA[0][r], sA[1][r]), fmaxf(sA[2][r], sA[3][r]));
            #pragma unroll
            for (int r = 0; r < 4; ++r) {
                #pragma unroll
                for (int off = 1; off <= 8; off <<= 1)
                    mx[r] = fmaxf(mx[r], __shfl_xor(mx[r], off, 64));
                float mn = fmaxf(m_[mt][r], mx[r]);
                corr[r] = __expf(m_[mt][r] - mn);
                m_[mt][r] = mn;
            }
            #pragma unroll
            for (int nt = 0; nt < 4; ++nt)
                #pragma unroll
                for (int r = 0; r < 4; ++r)
                    sA[nt][r] = __expf(sA[nt][r] - m_[mt][r]);
            #pragma unroll
            for (int r = 0; r < 4; ++r) {
                rs[r] = sA[0][r] + sA[1][r] + sA[2][r] + sA[3][r];
                #pragma unroll
                for (int off = 1; off <= 8; off <<= 1)
                    rs[r] += __shfl_xor(rs[r], off, 64);
                l_[mt][r] = l_[mt][r]*corr[r] + rs[r];
            }
            #pragma unroll
            for (int dt = 0; dt < 4; ++dt)
                #pragma unroll
                for (int r = 0; r < 4; ++r)
                    accO[mt][dt][r] *= corr[r];

            // P -> per-wave LDS (bf16), 16x64 tile
            #pragma unroll
            for (int nt = 0; nt < 4; ++nt)
                #pragma unroll
                for (int r = 0; r < 4; ++r) {
                    int row_l = rsub + r;
                    *(__hip_bfloat16*)(Pw + ((row_l*128 + (nt*16 + fr)*2) ^ ((row_l&7)<<4))) =
                        __float2bfloat16(sA[nt][r]);
                }

            // O += P @ V
            #pragma unroll
            for (int ks2 = 0; ks2 < 2; ++ks2) {
                short8v ap = *(const short8v*)(Pw + ((fr*128 + ks2*64 + g*16) ^ ((fr&7)<<4)));
                #pragma unroll
                for (int dt = 0; dt < 4; ++dt) {
                    int vrow = dt*16 + fr;
                    short8v bv = *(const short8v*)(Vb + ((vrow*128 + ks2*64 + g*16) ^ ((vrow&7)<<4)));
                    accO[mt][dt] = __builtin_amdgcn_mfma_f32_16x16x32_bf16(ap, bv, accO[mt][dt], 0, 0, 0);
                }
            }
        }

        if (t < tmax) stage_write(&KB[bf^1][0], &VB[bf^1][0], skey, sdg, kvn);
        __syncthreads();
    }

    // epilogue: O/l -> per-wave LDS -> coalesced bf16 stores
    #pragma unroll
    for (int mt = 0; mt < 2; ++mt) {
        const int grp = mt ? grp1 : grp0;
        float inv[4];
        #pragma unroll
        for (int r = 0; r < 4; ++r) inv[r] = 1.0f / l_[mt][r];
        #pragma unroll
        for (int dt = 0; dt < 4; ++dt)
            #pragma unroll
            for (int r = 0; r < 4; ++r) {
                int row_l = rsub + r;
                *(__hip_bfloat16*)(Pw + ((row_l*128 + (dt*16 + fr)*2) ^ ((row_l&7)<<4))) =
                    __float2bfloat16(accO[mt][dt][r] * inv[r]);
            }
        #pragma unroll
        for (int c = 0; c < 2; ++c) {
            int row_l = c*8 + (lane >> 3);
            size_t grow = (size_t)(srow + grp*16 + row_l);
            uint4 v = *(const uint4*)(Pw + ((row_l*128 + (lane&7)*16) ^ ((row_l&7)<<4)));
            *(uint4*)((char*)(ao + grow*DMODEL + h*DH) + (lane&7)*16) = v;
        }
    }
}

extern "C" void kernel_launch(void* const* d_in, const int* in_sizes, int n_in,
                              void* d_out, int out_size, void* d_ws, size_t ws_size,
                              hipStream_t stream) {
    const float* seq  = (const float*)d_in[0];
    const float* g    = (const float*)d_in[1];
    const float* wqkv = (const float*)d_in[2];
    const float* wout = (const float*)d_in[3];
    const float* pm   = (const float*)d_in[4];
    float* out = (float*)d_out;

    char* ws = (char*)d_ws;
    float* qkv            = (float*)ws;                                   // 96 MB
    __hip_bfloat16* xb    = (__hip_bfloat16*)(ws + 100663296);            // 16 MB (x, later ao)
    __hip_bfloat16* wqkvt = (__hip_bfloat16*)(ws + 100663296 + 16777216); // 6 MB
    __hip_bfloat16* woutt = (__hip_bfloat16*)(ws + 100663296 + 16777216 + 6291456); // 2 MB
    float* tab            = (float*)(ws + 100663296 + 16777216 + 6291456 + 2097152); // 1 MB

    rope_table<<<(NTOK*32)/256, 256, 0, stream>>>(tab);
    transpose_bf16<<<dim3(QKVC/32, DMODEL/32), 256, 0, stream>>>(wqkv, wqkvt, DMODEL, QKVC);
    transpose_bf16<<<dim3(DMODEL/32, DMODEL/32), 256, 0, stream>>>(wout, woutt, DMODEL, DMODEL);
    rmsnorm_bf16<<<ROWS, 256, 0, stream>>>(seq, g, xb);
    gemm_bf16<<<dim3(QKVC/128, ROWS/128), 256, 0, stream>>>(xb, wqkvt, qkv, ROWS, QKVC, DMODEL);
    rope_apply<<<(ROWS*2048/4)/256, 256, 0, stream>>>(qkv, tab);
    attn_mfma<<<dim3(16, 16, 2), 512, 0, stream>>>(qkv, pm, xb);
    gemm_bf16<<<dim3(DMODEL/128, ROWS/128), 256, 0, stream>>>(xb, woutt, out, ROWS, DMODEL, DMODEL);
}

// Round 6
// 180.884 us; speedup vs baseline: 1.7214x; 1.2103x over previous
//
#include <hip/hip_runtime.h>
#include <hip/hip_bf16.h>

typedef __attribute__((ext_vector_type(8))) short short8v;
typedef __attribute__((ext_vector_type(4))) float f32x4;

#define B_ 2
#define NTOK 4096
#define DMODEL 1024
#define HEADS_ 16
#define DH 64
#define SEG_ 512
#define PMEM 16
#define ROWS 8192      // B_*NTOK
#define QKVC 3072

// ---------------- RMSNorm -> bf16 ----------------
__global__ __launch_bounds__(256) void rmsnorm_bf16(const float* __restrict__ seq,
                                                    const float* __restrict__ g,
                                                    __hip_bfloat16* __restrict__ x) {
    int row = blockIdx.x;
    const float4* in = (const float4*)(seq + (size_t)row * DMODEL);
    int tid = threadIdx.x;
    float4 v = in[tid];
    float ss = v.x*v.x + v.y*v.y + v.z*v.z + v.w*v.w;
    #pragma unroll
    for (int off = 32; off >= 1; off >>= 1) ss += __shfl_xor(ss, off, 64);
    __shared__ float red[4];
    if ((tid & 63) == 0) red[tid >> 6] = ss;
    __syncthreads();
    float tot = red[0] + red[1] + red[2] + red[3];
    float scale = rsqrtf(tot * (1.0f/(float)DMODEL) + 1.1920929e-7f);
    float4 gv = ((const float4*)g)[tid];
    union { ushort4 u; __hip_bfloat16 h[4]; } pk;
    pk.h[0] = __float2bfloat16(v.x*scale*gv.x);
    pk.h[1] = __float2bfloat16(v.y*scale*gv.y);
    pk.h[2] = __float2bfloat16(v.z*scale*gv.z);
    pk.h[3] = __float2bfloat16(v.w*scale*gv.w);
    ((ushort4*)(x + (size_t)row * DMODEL))[tid] = pk.u;
}

// ---------------- transpose + convert: W[K,N] f32 -> Wt[N,K] bf16 ----------
__global__ __launch_bounds__(256) void transpose_bf16(const float* __restrict__ W,
                                                      __hip_bfloat16* __restrict__ Wt,
                                                      int K, int N) {
    __shared__ float t[32][33];
    int n0 = blockIdx.x * 32, k0 = blockIdx.y * 32;
    int c = threadIdx.x & 31, r = threadIdx.x >> 5;
    #pragma unroll
    for (int rr = 0; rr < 32; rr += 8)
        t[rr + r][c] = W[(size_t)(k0 + rr + r)*N + n0 + c];
    __syncthreads();
    #pragma unroll
    for (int rr = 0; rr < 32; rr += 8)
        Wt[(size_t)(n0 + rr + r)*K + k0 + c] = __float2bfloat16(t[c][rr + r]);
}

// ---------------- RoPE cos/sin table; pm f32 -> bf16 -----------------------
__global__ __launch_bounds__(256) void rope_table(float* __restrict__ tab) {
    int idx = blockIdx.x*256 + threadIdx.x;     // NTOK*32 threads
    int n = idx >> 5, p = idx & 31;
    float inv = powf(10000.f, -(float)p * (1.f/32.f));
    float a = (float)n * inv;
    float sn, cs;
    sincosf(a, &sn, &cs);
    tab[(size_t)n*64 + 2*p]     = cs;
    tab[(size_t)n*64 + 2*p + 1] = sn;
}

__global__ __launch_bounds__(256) void pm_bf16(const float* __restrict__ pm,
                                               __hip_bfloat16* __restrict__ pmb) {
    int idx = blockIdx.x*256 + threadIdx.x;     // 2*16*16*64 = 32768
    pmb[idx] = __float2bfloat16(pm[idx]);
}

// ---------------- bf16 MFMA GEMM: C[M,N] = A[M,K] @ Bt[N,K]^T --------------
// OutT: float (out-proj) or bf16 (qkv). ROPE: fuse interleaved rotary on
// cols < 2048 (block-uniform since 2048 is a 128-tile boundary).
__device__ __forceinline__ void gld16(const __hip_bfloat16* g, __hip_bfloat16* l) {
    __builtin_amdgcn_global_load_lds((const __attribute__((address_space(1))) void*)g,
                                     (__attribute__((address_space(3))) void*)l, 16, 0, 0);
}
__device__ __forceinline__ void storeC(float* p, float v) { *p = v; }
__device__ __forceinline__ void storeC(__hip_bfloat16* p, float v) { *p = __float2bfloat16(v); }

template<typename OutT, bool ROPE>
__global__ __launch_bounds__(256, 2) void gemm_t(const __hip_bfloat16* __restrict__ A,
                                                 const __hip_bfloat16* __restrict__ Bt,
                                                 OutT* __restrict__ C,
                                                 const float* __restrict__ tab,
                                                 int M, int N, int K) {
    __shared__ __hip_bfloat16 As[128*32];
    __shared__ __hip_bfloat16 Bs[128*32];
    const int tid = threadIdx.x;
    const int wid = tid >> 6, lane = tid & 63;
    const int bm = blockIdx.y * 128, bn = blockIdx.x * 128;
    const int wm = (wid >> 1) * 64, wn = (wid & 1) * 64;

    f32x4 acc[4][4];
    #pragma unroll
    for (int i = 0; i < 4; ++i)
        #pragma unroll
        for (int j = 0; j < 4; ++j)
            acc[i][j] = (f32x4){0.f, 0.f, 0.f, 0.f};

    const int c0 = wid*64 + lane;
    const int c1 = 256 + c0;
    const int r0 = c0 >> 2, kg0 = (c0 & 3) << 3;
    const int r1 = c1 >> 2, kg1 = (c1 & 3) << 3;
    const __hip_bfloat16* A0 = A + (size_t)(bm + r0)*K + kg0;
    const __hip_bfloat16* A1 = A + (size_t)(bm + r1)*K + kg1;
    const __hip_bfloat16* B0 = Bt + (size_t)(bn + r0)*K + kg0;
    const __hip_bfloat16* B1 = Bt + (size_t)(bn + r1)*K + kg1;

    const int fr = lane & 15;
    const int fk = (lane >> 4) << 3;

    for (int k0 = 0; k0 < K; k0 += 32) {
        gld16(A0 + k0, As + wid*512);
        gld16(A1 + k0, As + 2048 + wid*512);
        gld16(B0 + k0, Bs + wid*512);
        gld16(B1 + k0, Bs + 2048 + wid*512);
        __syncthreads();

        short8v a[4], b[4];
        #pragma unroll
        for (int mt = 0; mt < 4; ++mt)
            a[mt] = *(const short8v*)&As[(wm + mt*16 + fr)*32 + fk];
        #pragma unroll
        for (int nt = 0; nt < 4; ++nt)
            b[nt] = *(const short8v*)&Bs[(wn + nt*16 + fr)*32 + fk];
        #pragma unroll
        for (int mt = 0; mt < 4; ++mt)
            #pragma unroll
            for (int nt = 0; nt < 4; ++nt)
                acc[mt][nt] = __builtin_amdgcn_mfma_f32_16x16x32_bf16(a[mt], b[nt], acc[mt][nt], 0, 0, 0);
        __syncthreads();
    }

    const int rsub = (lane >> 4) << 2;
    if (ROPE && bn < 2048) {
        // interleaved rotary: partner col value lives in lane^1
        #pragma unroll
        for (int mt = 0; mt < 4; ++mt) {
            int rbase = bm + wm + mt*16 + rsub;
            #pragma unroll
            for (int nt = 0; nt < 4; ++nt) {
                int col = bn + wn + nt*16 + fr;
                int d = nt*16 + fr;            // col & 63
                int dc = d & ~1;
                #pragma unroll
                for (int r = 0; r < 4; ++r) {
                    float v = acc[mt][nt][r];
                    float pv = __shfl_xor(v, 1, 64);
                    int n = (rbase + r) & (NTOK - 1);
                    const float* tb = tab + (size_t)n*64;
                    float cs = tb[dc], sn = tb[dc+1];
                    float o = v*cs + ((d & 1) ? pv*sn : -pv*sn);
                    storeC(&C[(size_t)(rbase + r)*N + col], o);
                }
            }
        }
    } else {
        #pragma unroll
        for (int mt = 0; mt < 4; ++mt) {
            int rbase = bm + wm + mt*16 + rsub;
            #pragma unroll
            for (int nt = 0; nt < 4; ++nt) {
                int col = bn + wn + nt*16 + fr;
                #pragma unroll
                for (int r = 0; r < 4; ++r)
                    storeC(&C[(size_t)(rbase + r)*N + col], acc[mt][nt][r]);
            }
        }
    }
}

// ---------------- MFMA flash attention (bf16 qkv) ---------------------------
// grid (16 seg, 16 head, 2 rb), 512 threads = 8 waves. 32 groups of 16 q-rows;
// block rb owns groups with parity rb; wave w owns groups {2w+rb, 30-2w+rb}.
// KV tiles of 64 keys (tile0 = 16 pmem + 48 seg keys), double-buffered LDS.
// K [key][d], V transposed [d][key], P per-wave [16][64]; XOR swizzle (row&7)<<4.
// Score scale 1/8 folded into exp args. l kept per-lane, reduced in epilogue.
// __launch_bounds__(512,2): (512,4) caps VGPR at 64 -> 0.5 GB scratch spills.
__device__ __forceinline__ void stage_load(const __hip_bfloat16* __restrict__ qkv,
                                           const __hip_bfloat16* __restrict__ pmb,
                                           int h, int srow, int tt, int skey, int sdg,
                                           uint4 kv[2]) {
    int kg = tt*64 + skey;
    if (kg < PMEM) {
        kv[0] = *(const uint4*)(pmb + ((size_t)h*PMEM + kg)*DH + sdg);
        kv[1] = *(const uint4*)(pmb + ((size_t)(HEADS_ + h)*PMEM + kg)*DH + sdg);
    } else {
        int r = min(kg - PMEM, SEG_ - 1);   // clamp tail (masked anyway)
        const __hip_bfloat16* bp = qkv + (size_t)(srow + r)*QKVC + h*DH + sdg;
        kv[0] = *(const uint4*)(bp + 1024);
        kv[1] = *(const uint4*)(bp + 2048);
    }
}

__device__ __forceinline__ void stage_write(char* Kb, char* Vb,
                                            int skey, int sdg, const uint4 kv[2]) {
    *(uint4*)(Kb + ((skey*128 + sdg*2) ^ ((skey&7)<<4))) = kv[0];
    union { uint4 u; ushort s[8]; } vv; vv.u = kv[1];
    #pragma unroll
    for (int j = 0; j < 8; ++j) {
        int d = sdg + j;
        *(ushort*)(Vb + ((d*128 + skey*2) ^ ((d&7)<<4))) = vv.s[j];
    }
}

__global__ __launch_bounds__(512, 2) void attn_mfma(const __hip_bfloat16* __restrict__ qkv,
                                                    const __hip_bfloat16* __restrict__ pmb,
                                                    __hip_bfloat16* __restrict__ ao) {
    __shared__ __hip_bfloat16 KB[2][4096];
    __shared__ __hip_bfloat16 VB[2][4096];
    __shared__ __hip_bfloat16 PB[8][1024];

    const int s = blockIdx.x, h = blockIdx.y, rb = blockIdx.z;
    const int srow = (s >> 3)*NTOK + (s & 7)*SEG_;
    const int tid = threadIdx.x;
    const int w = tid >> 6, lane = tid & 63;
    const int g = lane >> 4, fr = lane & 15;
    const int rsub = g * 4;
    char* Pw = (char*)&PB[w][0];

    const int grp0 = 2*w + rb;
    const int grp1 = 30 - 2*w + rb;
    const int tmax = 7 + rb;

    // Q fragments (raw bf16; 1/8 scale folded into softmax exp)
    short8v aq[2][2];
    #pragma unroll
    for (int mt = 0; mt < 2; ++mt) {
        int grp = mt ? grp1 : grp0;
        const __hip_bfloat16* qp = qkv + (size_t)(srow + grp*16 + fr)*QKVC + h*DH;
        #pragma unroll
        for (int ks = 0; ks < 2; ++ks)
            aq[mt][ks] = *(const short8v*)(qp + ks*32 + g*8);
    }

    f32x4 accO[2][4];
    float m_[2][4], l_[2][4];
    #pragma unroll
    for (int mt = 0; mt < 2; ++mt) {
        #pragma unroll
        for (int dt = 0; dt < 4; ++dt) accO[mt][dt] = (f32x4){0.f,0.f,0.f,0.f};
        #pragma unroll
        for (int r = 0; r < 4; ++r) { m_[mt][r] = -1e30f; l_[mt][r] = 0.f; }
    }

    const int skey = tid >> 3, sdg = (tid & 7) * 8;

    {   // prologue: stage tile 0
        uint4 kv[2];
        stage_load(qkv, pmb, h, srow, 0, skey, sdg, kv);
        stage_write((char*)&KB[0][0], (char*)&VB[0][0], skey, sdg, kv);
    }
    __syncthreads();

    for (int t = 0; t <= tmax; ++t) {
        const int bf = t & 1;
        uint4 kvn[2];
        if (t < tmax) stage_load(qkv, pmb, h, srow, t + 1, skey, sdg, kvn);

        char* Kb = (char*)&KB[bf][0];
        char* Vb = (char*)&VB[bf][0];

        short8v bk[4][2];
        #pragma unroll
        for (int nt = 0; nt < 4; ++nt)
            #pragma unroll
            for (int ks = 0; ks < 2; ++ks) {
                int row = nt*16 + fr;
                bk[nt][ks] = *(const short8v*)(Kb + ((row*128 + ks*64 + g*16) ^ ((row&7)<<4)));
            }

        #pragma unroll
        for (int mt = 0; mt < 2; ++mt) {
            const int qb = (mt ? grp1 : grp0) * 16;
            if (t > 0 && t*64 > qb + 31) continue;       // fully masked tile

            f32x4 sA[4];
            #pragma unroll
            for (int nt = 0; nt < 4; ++nt) sA[nt] = (f32x4){0.f,0.f,0.f,0.f};
            #pragma unroll
            for (int ks = 0; ks < 2; ++ks)
                #pragma unroll
                for (int nt = 0; nt < 4; ++nt)
                    sA[nt] = __builtin_amdgcn_mfma_f32_16x16x32_bf16(aq[mt][ks], bk[nt][ks], sA[nt], 0, 0, 0);

            if (!(t*64 + 63 <= qb + 16)) {               // need masking
                #pragma unroll
                for (int nt = 0; nt < 4; ++nt) {
                    int kg2 = t*64 + nt*16 + fr;
                    #pragma unroll
                    for (int r = 0; r < 4; ++r) {
                        int irow = qb + rsub + r;
                        if (!((kg2 < PMEM) || (kg2 <= irow + PMEM))) sA[nt][r] = -1e30f;
                    }
                }
            }

            float mx[4], corr[4];
            #pragma unroll
            for (int r = 0; r < 4; ++r)
                mx[r] = fmaxf(fmaxf(sA[0][r], sA[1][r]), fmaxf(sA[2][r], sA[3][r]));
            #pragma unroll
            for (int r = 0; r < 4; ++r) {
                #pragma unroll
                for (int off = 1; off <= 8; off <<= 1)
                    mx[r] = fmaxf(mx[r], __shfl_xor(mx[r], off, 64));
                float mn = fmaxf(m_[mt][r], mx[r]);
                corr[r] = __expf((m_[mt][r] - mn)*0.125f);
                m_[mt][r] = mn;
            }
            #pragma unroll
            for (int nt = 0; nt < 4; ++nt)
                #pragma unroll
                for (int r = 0; r < 4; ++r)
                    sA[nt][r] = __expf((sA[nt][r] - m_[mt][r])*0.125f);
            #pragma unroll
            for (int r = 0; r < 4; ++r) {
                float lp = sA[0][r] + sA[1][r] + sA[2][r] + sA[3][r];
                l_[mt][r] = l_[mt][r]*corr[r] + lp;      // per-lane partial
            }
            #pragma unroll
            for (int dt = 0; dt < 4; ++dt)
                #pragma unroll
                for (int r = 0; r < 4; ++r)
                    accO[mt][dt][r] *= corr[r];

            // P -> per-wave LDS (bf16), 16x64 tile
            #pragma unroll
            for (int nt = 0; nt < 4; ++nt)
                #pragma unroll
                for (int r = 0; r < 4; ++r) {
                    int row_l = rsub + r;
                    *(__hip_bfloat16*)(Pw + ((row_l*128 + (nt*16 + fr)*2) ^ ((row_l&7)<<4))) =
                        __float2bfloat16(sA[nt][r]);
                }

            // O += P @ V
            #pragma unroll
            for (int ks2 = 0; ks2 < 2; ++ks2) {
                short8v ap = *(const short8v*)(Pw + ((fr*128 + ks2*64 + g*16) ^ ((fr&7)<<4)));
                #pragma unroll
                for (int dt = 0; dt < 4; ++dt) {
                    int vrow = dt*16 + fr;
                    short8v bv = *(const short8v*)(Vb + ((vrow*128 + ks2*64 + g*16) ^ ((vrow&7)<<4)));
                    accO[mt][dt] = __builtin_amdgcn_mfma_f32_16x16x32_bf16(ap, bv, accO[mt][dt], 0, 0, 0);
                }
            }
        }

        if (t < tmax) stage_write((char*)&KB[bf^1][0], (char*)&VB[bf^1][0], skey, sdg, kvn);
        __syncthreads();
    }

    // epilogue: reduce l across the 16-lane group, then O/l -> LDS -> stores
    #pragma unroll
    for (int mt = 0; mt < 2; ++mt) {
        const int grp = mt ? grp1 : grp0;
        float inv[4];
        #pragma unroll
        for (int r = 0; r < 4; ++r) {
            float lt = l_[mt][r];
            #pragma unroll
            for (int off = 1; off <= 8; off <<= 1) lt += __shfl_xor(lt, off, 64);
            inv[r] = 1.0f / lt;
        }
        #pragma unroll
        for (int dt = 0; dt < 4; ++dt)
            #pragma unroll
            for (int r = 0; r < 4; ++r) {
                int row_l = rsub + r;
                *(__hip_bfloat16*)(Pw + ((row_l*128 + (dt*16 + fr)*2) ^ ((row_l&7)<<4))) =
                    __float2bfloat16(accO[mt][dt][r] * inv[r]);
            }
        #pragma unroll
        for (int c = 0; c < 2; ++c) {
            int row_l = c*8 + (lane >> 3);
            size_t grow = (size_t)(srow + grp*16 + row_l);
            uint4 v = *(const uint4*)(Pw + ((row_l*128 + (lane&7)*16) ^ ((row_l&7)<<4)));
            *(uint4*)((char*)(ao + grow*DMODEL + h*DH) + (lane&7)*16) = v;
        }
    }
}

extern "C" void kernel_launch(void* const* d_in, const int* in_sizes, int n_in,
                              void* d_out, int out_size, void* d_ws, size_t ws_size,
                              hipStream_t stream) {
    const float* seq  = (const float*)d_in[0];
    const float* g    = (const float*)d_in[1];
    const float* wqkv = (const float*)d_in[2];
    const float* wout = (const float*)d_in[3];
    const float* pm   = (const float*)d_in[4];
    float* out = (float*)d_out;

    char* ws = (char*)d_ws;
    __hip_bfloat16* qkvb  = (__hip_bfloat16*)ws;                          // 48 MB
    __hip_bfloat16* xb    = (__hip_bfloat16*)(ws + 50331648);             // 16 MB (x, later ao)
    __hip_bfloat16* wqkvt = (__hip_bfloat16*)(ws + 50331648 + 16777216);  // 6 MB
    __hip_bfloat16* woutt = (__hip_bfloat16*)(ws + 50331648 + 16777216 + 6291456); // 2 MB
    float* tab            = (float*)(ws + 50331648 + 16777216 + 6291456 + 2097152); // 1 MB
    __hip_bfloat16* pmb   = (__hip_bfloat16*)(ws + 50331648 + 16777216 + 6291456 + 2097152 + 1048576); // 64 KB

    rope_table<<<(NTOK*32)/256, 256, 0, stream>>>(tab);
    pm_bf16<<<(2*HEADS_*PMEM*DH)/256, 256, 0, stream>>>(pm, pmb);
    transpose_bf16<<<dim3(QKVC/32, DMODEL/32), 256, 0, stream>>>(wqkv, wqkvt, DMODEL, QKVC);
    transpose_bf16<<<dim3(DMODEL/32, DMODEL/32), 256, 0, stream>>>(wout, woutt, DMODEL, DMODEL);
    rmsnorm_bf16<<<ROWS, 256, 0, stream>>>(seq, g, xb);
    gemm_t<__hip_bfloat16, true><<<dim3(QKVC/128, ROWS/128), 256, 0, stream>>>(xb, wqkvt, qkvb, tab, ROWS, QKVC, DMODEL);
    attn_mfma<<<dim3(16, 16, 2), 512, 0, stream>>>(qkvb, pmb, xb);
    gemm_t<float, false><<<dim3(DMODEL/128, ROWS/128), 256, 0, stream>>>(xb, woutt, out, nullptr, ROWS, DMODEL, DMODEL);
}